// Round 3
// baseline (2755.572 us; speedup 1.0000x reference)
//
#include <hip/hip_runtime.h>
#include <hip/hip_bf16.h>
#include <cstddef>

// Problem constants
constexpr int B = 128;
constexpr int T = 500;
constexpr int C = 128;     // n_maps
constexpr int CIN = 80;    // n_mels
constexpr int NL = 35;     // labels
constexpr size_t NBCT = (size_t)B * C * T;  // 8,192,000 floats
constexpr int WPAD = 132;                   // LDS i-stride (0 bank conflicts, measured R4)
constexpr int I0 = 96;                      // conv0 padded input channels
constexpr int IPAD0 = 104;                  // conv0 LDS i-stride
constexpr int NT = 64;                      // conv t-tile
constexpr int NSLOT = 49;                   // stats slots: 16*(t1,t3,t2) + conv0

typedef __attribute__((ext_vector_type(8))) _Float16 half8;  // 8 fp16 = 4 VGPR
typedef __attribute__((ext_vector_type(4))) _Float16 half4;
typedef __attribute__((ext_vector_type(4))) float f32x4;

// Static device scratch. All activation tensors in [b][t][c] layout.
__device__ float g_z[NBCT];
__device__ float g_acc[NBCT];
__device__ float g_zin[NBCT];
__device__ float g_t1[NBCT];
__device__ float g_t2[NBCT];
__device__ float g_t3[NBCT];
__device__ float g_S[NSLOT * C], g_Q[NSLOT * C];  // global stat accumulators
__device__ float g_featp[B * 4 * C];              // head partial sums
// conv0 weights, layout [kw][o][i] (i-stride I0), fp16
__device__ _Float16 g_w0f[3 * C * I0];
// main conv weights, MFMA-native layout [kw][kseg=i>>3][o][j=i&7], fp16
__device__ _Float16 g_w1f[9 * C * C];
__device__ _Float16 g_w2f[9 * C * C];
__device__ _Float16 g_w3f[1 * C * C];

// ---------------------------------------------------------------------------
// Zero the stat accumulators (once per launch, up front).
// ---------------------------------------------------------------------------
__global__ __launch_bounds__(256) void zero_stats(float* __restrict__ S,
                                                  float* __restrict__ Q) {
  int i = blockIdx.x * 256 + threadIdx.x;
  if (i < NSLOT * C) {
    S[i] = 0.f;
    Q[i] = 0.f;
  }
}

// ---------------------------------------------------------------------------
// Weight prep: w [O][I][KW] fp32 -> fp16, layout [kw][i>>3][o][i&7]
// ---------------------------------------------------------------------------
template <int KW>
__global__ __launch_bounds__(256) void prep_weights_f16(
    const float* __restrict__ w, _Float16* __restrict__ wf) {
  int idx = blockIdx.x * 256 + threadIdx.x;
  if (idx >= C * C * KW) return;
  int kw = idx % KW;
  int i = (idx / KW) % C;
  int o = idx / (KW * C);
  size_t dst = (((size_t)kw * 16 + (i >> 3)) * C + o) * 8 + (i & 7);
  wf[dst] = (_Float16)w[idx];
}

// conv0 weights: w0 [O=128][I=80][3] -> [3][O][I0=96] fp16 (zero-padded i>=80)
__global__ __launch_bounds__(256) void prep_w0_f16(
    const float* __restrict__ w, _Float16* __restrict__ wf) {
  int idx = blockIdx.x * 256 + threadIdx.x;
  if (idx >= 3 * C * I0) return;
  int i = idx % I0;
  int o = (idx / I0) % C;
  int kw = idx / (I0 * C);
  float v = 0.f;
  if (i < CIN) v = w[((size_t)o * CIN + i) * 3 + kw];
  wf[((size_t)kw * C + o) * I0 + i] = (_Float16)v;
}

// ---------------------------------------------------------------------------
// Epilogue: store D tiles + per-channel partial stats into LDS ssum/ssq.
// D layout (16x16x32): col(t)=lane&15, row(o)=quad*4+reg.
// ---------------------------------------------------------------------------
template <int NG, int NTG>
__device__ inline void store_and_stats(f32x4 (&dacc)[NG][NTG],
                                       float* __restrict__ outb,
                                       float* __restrict__ ssum,
                                       float* __restrict__ ssq, int tbase,
                                       int og0, int quad, int m15) {
#pragma unroll
  for (int g = 0; g < NG; g++) {
    float rs[4] = {0.f, 0.f, 0.f, 0.f}, rq[4] = {0.f, 0.f, 0.f, 0.f};
#pragma unroll
    for (int tg = 0; tg < NTG; tg++) {
      int t = tbase + tg * 16 + m15;
      bool valid = t < T;
      f32x4 d = dacc[g][tg];
      if (valid)
        *(f32x4*)(outb + (size_t)t * C + (og0 + g) * 16 + quad * 4) = d;
#pragma unroll
      for (int r = 0; r < 4; r++) {
        float v = valid ? d[r] : 0.f;
        rs[r] += v;
        rq[r] += v * v;
      }
    }
#pragma unroll
    for (int sh = 1; sh < 16; sh <<= 1) {
#pragma unroll
      for (int r = 0; r < 4; r++) {
        rs[r] += __shfl_xor(rs[r], sh);
        rq[r] += __shfl_xor(rq[r], sh);
      }
    }
    if (m15 == 0) {
      int o = (og0 + g) * 16 + quad * 4;
#pragma unroll
      for (int r = 0; r < 4; r++) {
        atomicAdd(&ssum[o + r], rs[r]);
        atomicAdd(&ssq[o + r], rq[r]);
      }
    }
  }
}

// ---------------------------------------------------------------------------
// Fused conv1 (KW=9, PAD=4) + conv3 (KW=1) from one LDS staging of zin.
// Software-pipelined A-frag loads (2 rounds/iter, named afA/afB pairs):
// round r+1's weight load issues before round r's MFMAs so L2 latency
// overlaps compute. Rounds 0..35 = conv1, 36..39 = conv3 (dacc3 live range
// kept short). Geometry: 4 waves x (NG=2 og x NTG=4 tg) — measured best.
// ---------------------------------------------------------------------------
__global__ __launch_bounds__(256, 4) void conv13(
    const float* __restrict__ in, const _Float16* __restrict__ w9,
    const _Float16* __restrict__ w1, float* __restrict__ out1,
    float* __restrict__ out3, float* __restrict__ gS1,
    float* __restrict__ gQ1, float* __restrict__ gS3,
    float* __restrict__ gQ3) {
  constexpr int PAD = 4;
  constexpr int ROWS = NT + 8;  // 72
  __shared__ __align__(16) _Float16 sh[ROWS * WPAD];
  __shared__ float ssum1[C], ssq1[C], ssum3[C], ssq3[C];

  const int tid = threadIdx.x;
  const int tile = blockIdx.x;
  const int b = blockIdx.y;
  const int t0 = tile * NT;

  if (tid < 128) {
    ssum1[tid] = 0.f; ssq1[tid] = 0.f;
    ssum3[tid] = 0.f; ssq3[tid] = 0.f;
  }
  __syncthreads();

  // Stage input rows [t0-PAD, t0-PAD+ROWS) as fp16 into LDS.
  const float* __restrict__ inb = in + (size_t)b * T * C;
  constexpr int NF4 = ROWS * (C / 4);
  for (int e = tid; e < NF4; e += 256) {
    int r = e >> 5;
    int c4 = e & 31;
    int t = t0 - PAD + r;
    float4 v = make_float4(0.f, 0.f, 0.f, 0.f);
    if (t >= 0 && t < T) v = ((const float4*)(inb + (size_t)t * C))[c4];
    half4 hv;
    hv[0] = (_Float16)v.x;
    hv[1] = (_Float16)v.y;
    hv[2] = (_Float16)v.z;
    hv[3] = (_Float16)v.w;
    *(half4*)&sh[r * WPAD + c4 * 4] = hv;
  }
  __syncthreads();

  const int wv = tid >> 6;
  const int lane = tid & 63;
  const int quad = lane >> 4;
  const int m15 = lane & 15;
  const int og0 = wv * 2;

  const half8* __restrict__ A9 = (const half8*)w9;
  const half8* __restrict__ A1 = (const half8*)w1;

  f32x4 dacc1[2][4];
  f32x4 dacc3[2][4];
#pragma unroll
  for (int g = 0; g < 2; g++)
#pragma unroll
    for (int tg = 0; tg < 4; tg++) {
      dacc1[g][tg] = f32x4{0.f, 0.f, 0.f, 0.f};
      dacc3[g][tg] = f32x4{0.f, 0.f, 0.f, 0.f};
    }

  auto ldA = [&](int r, half8 (&af)[2]) {
    const half8* __restrict__ A = (r < 36) ? A9 : A1;
    const int kw = (r < 36) ? (r >> 2) : 0;
    const int ic = r & 3;
    const int base = (kw * 16 + ic * 4 + quad) * C;
    af[0] = A[base + og0 * 16 + m15];
    af[1] = A[base + (og0 + 1) * 16 + m15];
  };

  auto round = [&](int r, half8 (&af)[2]) {
    const int kw = (r < 36) ? (r >> 2) : 0;
    const int ic = r & 3;
    const int rofs = (r < 36) ? kw : PAD;  // conv3 reads the un-shifted rows
    const int kof = ic * 32 + quad * 8;
    half8 bf[4];
#pragma unroll
    for (int tg = 0; tg < 4; tg++)
      bf[tg] = *(const half8*)(sh + (tg * 16 + m15 + rofs) * WPAD + kof);
#pragma unroll
    for (int g = 0; g < 2; g++)
#pragma unroll
      for (int tg = 0; tg < 4; tg++) {
        if (r < 36)
          dacc1[g][tg] = __builtin_amdgcn_mfma_f32_16x16x32_f16(
              af[g], bf[tg], dacc1[g][tg], 0, 0, 0);
        else
          dacc3[g][tg] = __builtin_amdgcn_mfma_f32_16x16x32_f16(
              af[g], bf[tg], dacc3[g][tg], 0, 0, 0);
      }
  };

  half8 afA[2], afB[2];
  ldA(0, afA);
#pragma unroll
  for (int r = 0; r < 40; r += 2) {
    ldA(r + 1, afB);
    round(r, afA);
    if (r + 2 < 40) ldA(r + 2, afA);
    round(r + 1, afB);
  }

  float* __restrict__ o1b = out1 + (size_t)b * T * C;
  float* __restrict__ o3b = out3 + (size_t)b * T * C;
  store_and_stats<2, 4>(dacc1, o1b, ssum1, ssq1, t0, og0, quad, m15);
  store_and_stats<2, 4>(dacc3, o3b, ssum3, ssq3, t0, og0, quad, m15);
  __syncthreads();
  if (tid < 128) {
    atomicAdd(&gS1[tid], ssum1[tid]);
    atomicAdd(&gQ1[tid], ssq1[tid]);
    atomicAdd(&gS3[tid], ssum3[tid]);
    atomicAdd(&gQ3[tid], ssq3[tid]);
  }
}

// ---------------------------------------------------------------------------
// conv2 (KW=9, PAD=4, BNRELU on staging) with the same pipelined A loads.
// ---------------------------------------------------------------------------
__global__ __launch_bounds__(256, 4) void conv2_bn(
    const float* __restrict__ in, const _Float16* __restrict__ wf,
    const float* __restrict__ bnS, const float* __restrict__ bnQ,
    float* __restrict__ out, float* __restrict__ gS, float* __restrict__ gQ) {
  constexpr int KW = 9, PAD = 4;
  constexpr int ROWS = NT + KW - 1;  // 72
  __shared__ __align__(16) _Float16 sh[ROWS * WPAD];
  __shared__ float ssum[C], ssq[C];
  __shared__ float sbm[C], sbr[C];

  const int tid = threadIdx.x;
  const int tile = blockIdx.x;
  const int b = blockIdx.y;
  const int t0 = tile * NT;

  if (tid < 128) {
    const float invn = 1.f / 64000.f;
    float m = bnS[tid] * invn;
    sbm[tid] = m;
    sbr[tid] = rsqrtf(bnQ[tid] * invn - m * m + 1e-5f);
    ssum[tid] = 0.f;
    ssq[tid] = 0.f;
  }
  __syncthreads();

  const float* __restrict__ inb = in + (size_t)b * T * C;
  constexpr int NF4 = ROWS * (C / 4);
  for (int e = tid; e < NF4; e += 256) {
    int r = e >> 5;
    int c4 = e & 31;
    int t = t0 - PAD + r;
    float4 v = make_float4(0.f, 0.f, 0.f, 0.f);
    if (t >= 0 && t < T) {
      v = ((const float4*)(inb + (size_t)t * C))[c4];
      int c = c4 * 4;
      v.x = fmaxf((v.x - sbm[c]) * sbr[c], 0.f);
      v.y = fmaxf((v.y - sbm[c + 1]) * sbr[c + 1], 0.f);
      v.z = fmaxf((v.z - sbm[c + 2]) * sbr[c + 2], 0.f);
      v.w = fmaxf((v.w - sbm[c + 3]) * sbr[c + 3], 0.f);
    }
    half4 hv;
    hv[0] = (_Float16)v.x;
    hv[1] = (_Float16)v.y;
    hv[2] = (_Float16)v.z;
    hv[3] = (_Float16)v.w;
    *(half4*)&sh[r * WPAD + c4 * 4] = hv;
  }
  __syncthreads();

  const int wv = tid >> 6;
  const int lane = tid & 63;
  const int quad = lane >> 4;
  const int m15 = lane & 15;
  const int og0 = wv * 2;

  const half8* __restrict__ Af = (const half8*)wf;

  f32x4 dacc[2][4];
#pragma unroll
  for (int g = 0; g < 2; g++)
#pragma unroll
    for (int tg = 0; tg < 4; tg++) dacc[g][tg] = f32x4{0.f, 0.f, 0.f, 0.f};

  auto ldA = [&](int r, half8 (&af)[2]) {
    const int kw = r >> 2;
    const int ic = r & 3;
    const int base = (kw * 16 + ic * 4 + quad) * C;
    af[0] = Af[base + og0 * 16 + m15];
    af[1] = Af[base + (og0 + 1) * 16 + m15];
  };

  auto round = [&](int r, half8 (&af)[2]) {
    const int kw = r >> 2;
    const int ic = r & 3;
    const int kof = ic * 32 + quad * 8;
    half8 bf[4];
#pragma unroll
    for (int tg = 0; tg < 4; tg++)
      bf[tg] = *(const half8*)(sh + (tg * 16 + m15 + kw) * WPAD + kof);
#pragma unroll
    for (int g = 0; g < 2; g++)
#pragma unroll
      for (int tg = 0; tg < 4; tg++)
        dacc[g][tg] = __builtin_amdgcn_mfma_f32_16x16x32_f16(
            af[g], bf[tg], dacc[g][tg], 0, 0, 0);
  };

  half8 afA[2], afB[2];
  ldA(0, afA);
#pragma unroll
  for (int r = 0; r < 36; r += 2) {
    ldA(r + 1, afB);
    round(r, afA);
    if (r + 2 < 36) ldA(r + 2, afA);
    round(r + 1, afB);
  }

  float* __restrict__ outb = out + (size_t)b * T * C;
  store_and_stats<2, 4>(dacc, outb, ssum, ssq, t0, og0, quad, m15);
  __syncthreads();
  if (tid < 128) {
    atomicAdd(&gS[tid], ssum[tid]);
    atomicAdd(&gQ[tid], ssq[tid]);
  }
}

// ---------------------------------------------------------------------------
// conv0: single fp16 16x16x32 MFMA. in x[B][80][T] (t fastest), K=96(pad) x 3.
// ---------------------------------------------------------------------------
__global__ __launch_bounds__(256) void conv0_mfma(
    const float* __restrict__ in, const _Float16* __restrict__ wf,
    float* __restrict__ out, float* __restrict__ gS, float* __restrict__ gQ) {
  constexpr int KW = 3, PAD = 1;
  constexpr int ROWS = NT + KW - 1;  // 66
  __shared__ __align__(16) _Float16 sh[ROWS * IPAD0];
  __shared__ float ssum[C], ssq[C];

  const int tid = threadIdx.x;
  const int tile = blockIdx.x;
  const int b = blockIdx.y;
  const int t0 = tile * NT;

  if (tid < 128) { ssum[tid] = 0.f; ssq[tid] = 0.f; }
  __syncthreads();

  const float* __restrict__ inb = in + (size_t)b * CIN * T;
  for (int e = tid; e < I0 * ROWS; e += 256) {
    int i = e / ROWS;
    int r = e % ROWS;
    int t = t0 - PAD + r;
    float v = 0.f;
    if (i < CIN && t >= 0 && t < T) v = inb[(size_t)i * T + t];
    sh[r * IPAD0 + i] = (_Float16)v;
  }
  __syncthreads();

  const int wv = tid >> 6;
  const int lane = tid & 63;
  const int quad = lane >> 4;
  const int m15 = lane & 15;
  const int og0 = wv * 2;

  f32x4 dacc[2][4];
#pragma unroll
  for (int g = 0; g < 2; g++)
#pragma unroll
    for (int tg = 0; tg < 4; tg++) dacc[g][tg] = f32x4{0.f, 0.f, 0.f, 0.f};

  for (int kw = 0; kw < KW; kw++) {
    const _Float16* __restrict__ wk = wf + (size_t)kw * C * I0;
#pragma unroll
    for (int ic = 0; ic < 3; ic++) {
      const int kof = ic * 32 + quad * 8;
      half8 af[2];
#pragma unroll
      for (int g = 0; g < 2; g++) {
        size_t off = (size_t)((og0 + g) * 16 + m15) * I0 + kof;
        af[g] = *(const half8*)(wk + off);
      }
      half8 bf[4];
#pragma unroll
      for (int tg = 0; tg < 4; tg++) {
        int off = (tg * 16 + m15 + kw) * IPAD0 + kof;
        bf[tg] = *(const half8*)(sh + off);
      }
#pragma unroll
      for (int g = 0; g < 2; g++)
#pragma unroll
        for (int tg = 0; tg < 4; tg++)
          dacc[g][tg] = __builtin_amdgcn_mfma_f32_16x16x32_f16(
              af[g], bf[tg], dacc[g][tg], 0, 0, 0);
    }
  }

  float* __restrict__ outb = out + (size_t)b * T * C;
  store_and_stats<2, 4>(dacc, outb, ssum, ssq, t0, og0, quad, m15);
  __syncthreads();
  if (tid < 128) {
    atomicAdd(&gS[tid], ssum[tid]);
    atomicAdd(&gQ[tid], ssq[tid]);
  }
}

// ---------------------------------------------------------------------------
// In-place z = relu((z - m[c]) * r[c]); m,r computed inline from S,Q.
// ---------------------------------------------------------------------------
__global__ __launch_bounds__(256) void apply_bn_relu(
    float* __restrict__ x, const float* __restrict__ S,
    const float* __restrict__ Q) {
  __shared__ float sm[C], sr[C];
  if (threadIdx.x < 128) {
    const float invn = 1.f / 64000.f;
    float m = S[threadIdx.x] * invn;
    sm[threadIdx.x] = m;
    sr[threadIdx.x] = rsqrtf(Q[threadIdx.x] * invn - m * m + 1e-5f);
  }
  __syncthreads();
  const size_t total4 = NBCT / 4;
  size_t stride = (size_t)gridDim.x * 256;
  for (size_t i4 = (size_t)blockIdx.x * 256 + threadIdx.x; i4 < total4;
       i4 += stride) {
    int c = (int)((i4 & 31) * 4);
    float4 v = ((float4*)x)[i4];
    v.x = fmaxf((v.x - sm[c]) * sr[c], 0.f);
    v.y = fmaxf((v.y - sm[c + 1]) * sr[c + 1], 0.f);
    v.z = fmaxf((v.z - sm[c + 2]) * sr[c + 2], 0.f);
    v.w = fmaxf((v.w - sm[c + 3]) * sr[c + 3], 0.f);
    ((float4*)x)[i4] = v;
  }
}

// ---------------------------------------------------------------------------
// combine: k = relu(bn2(t2) + relu(bn3(t3))); RK4 update. Stats inline.
// ---------------------------------------------------------------------------
__global__ __launch_bounds__(256) void combine_kernel(
    const float* __restrict__ t2, const float* __restrict__ t3,
    const float* __restrict__ S2, const float* __restrict__ Q2,
    const float* __restrict__ S3, const float* __restrict__ Q3,
    const float* __restrict__ z, float* __restrict__ acc,
    float* __restrict__ zout, float wacc, float anext, int init, int fin) {
  __shared__ float sm2[C], sr2[C], sm3[C], sr3[C];
  if (threadIdx.x < 128) {
    const float invn = 1.f / 64000.f;
    float m2v = S2[threadIdx.x] * invn;
    sm2[threadIdx.x] = m2v;
    sr2[threadIdx.x] = rsqrtf(Q2[threadIdx.x] * invn - m2v * m2v + 1e-5f);
    float m3v = S3[threadIdx.x] * invn;
    sm3[threadIdx.x] = m3v;
    sr3[threadIdx.x] = rsqrtf(Q3[threadIdx.x] * invn - m3v * m3v + 1e-5f);
  }
  __syncthreads();
  const size_t total4 = NBCT / 4;
  size_t stride = (size_t)gridDim.x * 256;
  for (size_t i4 = (size_t)blockIdx.x * 256 + threadIdx.x; i4 < total4;
       i4 += stride) {
    int c = (int)((i4 & 31) * 4);
    size_t off = i4 * 4;
    float4 v2 = *(const float4*)(t2 + off);
    float4 v3 = *(const float4*)(t3 + off);
    float4 vz = *(const float4*)(z + off);
    float4 k;
    k.x = fmaxf((v2.x - sm2[c]) * sr2[c] + fmaxf((v3.x - sm3[c]) * sr3[c], 0.f), 0.f);
    k.y = fmaxf((v2.y - sm2[c + 1]) * sr2[c + 1] + fmaxf((v3.y - sm3[c + 1]) * sr3[c + 1], 0.f), 0.f);
    k.z = fmaxf((v2.z - sm2[c + 2]) * sr2[c + 2] + fmaxf((v3.z - sm3[c + 2]) * sr3[c + 2], 0.f), 0.f);
    k.w = fmaxf((v2.w - sm2[c + 3]) * sr2[c + 3] + fmaxf((v3.w - sm3[c + 3]) * sr3[c + 3], 0.f), 0.f);
    float4 va;
    if (init) {
      va.x = wacc * k.x; va.y = wacc * k.y; va.z = wacc * k.z; va.w = wacc * k.w;
    } else {
      va = *(const float4*)(acc + off);
      va.x += wacc * k.x; va.y += wacc * k.y; va.z += wacc * k.z; va.w += wacc * k.w;
    }
    if (!fin) *(float4*)(acc + off) = va;
    float4 vo;
    if (fin) {
      vo.x = vz.x + anext * va.x; vo.y = vz.y + anext * va.y;
      vo.z = vz.z + anext * va.z; vo.w = vz.w + anext * va.w;
    } else {
      vo.x = vz.x + anext * k.x; vo.y = vz.y + anext * k.y;
      vo.z = vz.z + anext * k.z; vo.w = vz.w + anext * k.w;
    }
    *(float4*)(zout + off) = vo;
  }
}

// ---------------------------------------------------------------------------
// head, phase 1: partial t-sums. grid (B, 4), each block sums 125 t's.
// ---------------------------------------------------------------------------
__global__ __launch_bounds__(256) void feat_part(
    const float* __restrict__ z, float* __restrict__ fp) {
  const int b = blockIdx.x;
  const int s = blockIdx.y;
  const int c = threadIdx.x & 127;
  const int h = threadIdx.x >> 7;
  const float* zb = z + (size_t)b * T * C;
  float sum = 0.f;
  for (int t = s * 125 + h; t < (s + 1) * 125; t += 2)
    sum += zb[(size_t)t * C + c];
  __shared__ float sf[2][C];
  sf[h][c] = sum;
  __syncthreads();
  if (threadIdx.x < 128)
    fp[((size_t)b * 4 + s) * C + threadIdx.x] =
        sf[0][threadIdx.x] + sf[1][threadIdx.x];
}

// head, phase 2: feat = sum(partials)/500; out = feat @ ow^T + ob.
__global__ __launch_bounds__(256) void head2(
    const float* __restrict__ fp, const float* __restrict__ ow,
    const float* __restrict__ ob, float* __restrict__ out) {
  const int b = blockIdx.x;
  __shared__ float feat[C];
  if (threadIdx.x < 128) {
    float s = 0.f;
#pragma unroll
    for (int p = 0; p < 4; p++) s += fp[((size_t)b * 4 + p) * C + threadIdx.x];
    feat[threadIdx.x] = s * (1.f / 500.f);
  }
  __syncthreads();
  if (threadIdx.x < NL) {
    int l = threadIdx.x;
    float o = ob[l];
    for (int j = 0; j < C; j++) o = fmaf(feat[j], ow[l * C + j], o);
    out[b * NL + l] = o;
  }
}

// ---------------------------------------------------------------------------
extern "C" void kernel_launch(void* const* d_in, const int* in_sizes, int n_in,
                              void* d_out, int out_size, void* d_ws,
                              size_t ws_size, hipStream_t stream) {
  const float* x  = (const float*)d_in[0];
  const float* w0 = (const float*)d_in[1];
  const float* w1 = (const float*)d_in[2];
  const float* w2 = (const float*)d_in[3];
  const float* w3 = (const float*)d_in[4];
  const float* ow = (const float*)d_in[5];
  const float* ob = (const float*)d_in[6];
  float* out = (float*)d_out;

  static float *z, *acc, *zin, *t1, *t2, *t3;
  static float *Sg, *Qg, *featp;
  static _Float16 *w0f, *w1f, *w2f, *w3f;
  static bool inited = false;
  if (!inited) {
    void* p;
#define GET(sym, var) hipGetSymbolAddress(&p, HIP_SYMBOL(sym)); var = (decltype(var))p;
    GET(g_z, z) GET(g_acc, acc) GET(g_zin, zin)
    GET(g_t1, t1) GET(g_t2, t2) GET(g_t3, t3)
    GET(g_S, Sg) GET(g_Q, Qg) GET(g_featp, featp)
    GET(g_w0f, w0f) GET(g_w1f, w1f) GET(g_w2f, w2f) GET(g_w3f, w3f)
#undef GET
    inited = true;
  }

  // Zero stat slots + weight prep (cheap, every launch)
  zero_stats<<<(NSLOT * C + 255) / 256, 256, 0, stream>>>(Sg, Qg);
  prep_w0_f16<<<(3 * C * I0 + 255) / 256, 256, 0, stream>>>(w0, w0f);
  prep_weights_f16<9><<<(C * C * 9 + 255) / 256, 256, 0, stream>>>(w1, w1f);
  prep_weights_f16<9><<<(C * C * 9 + 255) / 256, 256, 0, stream>>>(w2, w2f);
  prep_weights_f16<1><<<(C * C * 1 + 255) / 256, 256, 0, stream>>>(w3, w3f);

  const dim3 convGrid(8, B);   // NT=64 tiles -> 1024 blocks
  const int ewGrid = 1024;
  const float dt = 0.25f;

  // conv0 -> bn -> relu (into z). Stats slot 48.
  float* S0 = Sg + 48 * C;
  float* Q0 = Qg + 48 * C;
  conv0_mfma<<<convGrid, 256, 0, stream>>>(x, w0f, z, S0, Q0);
  apply_bn_relu<<<ewGrid, 256, 0, stream>>>(z, S0, Q0);

  const float waccs[4] = {1.f, 2.f, 2.f, 1.f};
  const float anexts[4] = {0.5f * dt, 0.5f * dt, dt, dt / 6.f};

  for (int step = 0; step < 4; step++) {
    for (int s = 0; s < 4; s++) {
      const float* zin_s = (s == 0) ? z : zin;
      int base = ((step * 4 + s) * 3) * C;   // slots: t1, t3, t2
      float* S1 = Sg + base;       float* Q1 = Qg + base;
      float* S3 = Sg + base + C;   float* Q3 = Qg + base + C;
      float* S2 = Sg + base + 2*C; float* Q2 = Qg + base + 2*C;
      conv13<<<convGrid, 256, 0, stream>>>(
          zin_s, w1f, w3f, t1, t3, S1, Q1, S3, Q3);
      conv2_bn<<<convGrid, 256, 0, stream>>>(
          t1, w2f, S1, Q1, t2, S2, Q2);
      combine_kernel<<<ewGrid, 256, 0, stream>>>(
          t2, t3, S2, Q2, S3, Q3, z, acc, (s == 3) ? z : zin,
          waccs[s], anexts[s], (s == 0) ? 1 : 0, (s == 3) ? 1 : 0);
    }
  }

  feat_part<<<dim3(B, 4), 256, 0, stream>>>(z, featp);
  head2<<<B, 256, 0, stream>>>(featp, ow, ob, out);
}

// Round 4
// 2405.411 us; speedup vs baseline: 1.1456x; 1.1456x over previous
//
#include <hip/hip_runtime.h>
#include <hip/hip_bf16.h>
#include <cstddef>

// Problem constants
constexpr int B = 128;
constexpr int T = 500;
constexpr int C = 128;     // n_maps
constexpr int CIN = 80;    // n_mels
constexpr int NL = 35;     // labels
constexpr size_t NBCT = (size_t)B * C * T;  // 8,192,000 floats
constexpr int WPAD = 132;                   // LDS i-stride (0 bank conflicts)
constexpr int I0 = 96;                      // conv0 padded input channels
constexpr int IPAD0 = 104;                  // conv0 LDS i-stride
constexpr int NT = 64;                      // conv t-tile
constexpr int NSLOT = 49;                   // stats slots: 16*(t1,t3,t2) + conv0

typedef __attribute__((ext_vector_type(8))) _Float16 half8;  // 8 fp16 = 4 VGPR
typedef __attribute__((ext_vector_type(4))) _Float16 half4;
typedef __attribute__((ext_vector_type(4))) float f32x4;

// Static device scratch. Activations in [b][t][c] layout.
__device__ float g_z[NBCT];          // RK4 state (fp32)
__device__ float g_acc[NBCT];        // RK4 k-accumulator (fp32)
__device__ _Float16 g_zi16[NBCT];    // conv input snapshot (fp16)
__device__ _Float16 g_t1[NBCT];      // conv1 out (fp16, pre-BN)
__device__ _Float16 g_t2[NBCT];      // conv2 out (fp16, pre-BN)
__device__ _Float16 g_t3[NBCT];      // conv3 out (fp16, pre-BN)
__device__ float g_S[NSLOT * C], g_Q[NSLOT * C];  // global stat accumulators
__device__ float g_featp[B * 4 * C];              // head partial sums
// conv0 weights, layout [kw][o][i] (i-stride I0), fp16
__device__ _Float16 g_w0f[3 * C * I0];
// main conv weights, MFMA-native layout [kw][kseg=i>>3][o][j=i&7], fp16
__device__ _Float16 g_w1f[9 * C * C];
__device__ _Float16 g_w2f[9 * C * C];
__device__ _Float16 g_w3f[1 * C * C];

__device__ inline half8 h8zero() {
  half8 v;
#pragma unroll
  for (int j = 0; j < 8; j++) v[j] = (_Float16)0.f;
  return v;
}

// ---------------------------------------------------------------------------
// Zero the stat accumulators (once per launch, up front).
// ---------------------------------------------------------------------------
__global__ __launch_bounds__(256) void zero_stats(float* __restrict__ S,
                                                  float* __restrict__ Q) {
  int i = blockIdx.x * 256 + threadIdx.x;
  if (i < NSLOT * C) {
    S[i] = 0.f;
    Q[i] = 0.f;
  }
}

// ---------------------------------------------------------------------------
// Weight prep: w [O][I][KW] fp32 -> fp16, layout [kw][i>>3][o][i&7]
// ---------------------------------------------------------------------------
template <int KW>
__global__ __launch_bounds__(256) void prep_weights_f16(
    const float* __restrict__ w, _Float16* __restrict__ wf) {
  int idx = blockIdx.x * 256 + threadIdx.x;
  if (idx >= C * C * KW) return;
  int kw = idx % KW;
  int i = (idx / KW) % C;
  int o = idx / (KW * C);
  size_t dst = (((size_t)kw * 16 + (i >> 3)) * C + o) * 8 + (i & 7);
  wf[dst] = (_Float16)w[idx];
}

// conv0 weights: w0 [O=128][I=80][3] -> [3][O][I0=96] fp16 (zero-padded i>=80)
__global__ __launch_bounds__(256) void prep_w0_f16(
    const float* __restrict__ w, _Float16* __restrict__ wf) {
  int idx = blockIdx.x * 256 + threadIdx.x;
  if (idx >= 3 * C * I0) return;
  int i = idx % I0;
  int o = (idx / I0) % C;
  int kw = idx / (I0 * C);
  float v = 0.f;
  if (i < CIN) v = w[((size_t)o * CIN + i) * 3 + kw];
  wf[((size_t)kw * C + o) * I0 + i] = (_Float16)v;
}

// ---------------------------------------------------------------------------
// Epilogues: store D tiles (fp32 or fp16 out) + per-channel partial stats.
// D layout (16x16x32): col(t)=lane&15, row(o)=quad*4+reg.
// ---------------------------------------------------------------------------
template <int NG, int NTG>
__device__ inline void store_and_stats_f(f32x4 (&dacc)[NG][NTG],
                                         float* __restrict__ outb,
                                         float* __restrict__ ssum,
                                         float* __restrict__ ssq, int tbase,
                                         int og0, int quad, int m15) {
#pragma unroll
  for (int g = 0; g < NG; g++) {
    float rs[4] = {0.f, 0.f, 0.f, 0.f}, rq[4] = {0.f, 0.f, 0.f, 0.f};
#pragma unroll
    for (int tg = 0; tg < NTG; tg++) {
      int t = tbase + tg * 16 + m15;
      bool valid = t < T;
      f32x4 d = dacc[g][tg];
      if (valid)
        *(f32x4*)(outb + (size_t)t * C + (og0 + g) * 16 + quad * 4) = d;
#pragma unroll
      for (int r = 0; r < 4; r++) {
        float v = valid ? d[r] : 0.f;
        rs[r] += v;
        rq[r] += v * v;
      }
    }
#pragma unroll
    for (int sh = 1; sh < 16; sh <<= 1) {
#pragma unroll
      for (int r = 0; r < 4; r++) {
        rs[r] += __shfl_xor(rs[r], sh);
        rq[r] += __shfl_xor(rq[r], sh);
      }
    }
    if (m15 == 0) {
      int o = (og0 + g) * 16 + quad * 4;
#pragma unroll
      for (int r = 0; r < 4; r++) {
        atomicAdd(&ssum[o + r], rs[r]);
        atomicAdd(&ssq[o + r], rq[r]);
      }
    }
  }
}

template <int NG, int NTG>
__device__ inline void store_and_stats_h(f32x4 (&dacc)[NG][NTG],
                                         _Float16* __restrict__ outb,
                                         float* __restrict__ ssum,
                                         float* __restrict__ ssq, int tbase,
                                         int og0, int quad, int m15) {
#pragma unroll
  for (int g = 0; g < NG; g++) {
    float rs[4] = {0.f, 0.f, 0.f, 0.f}, rq[4] = {0.f, 0.f, 0.f, 0.f};
#pragma unroll
    for (int tg = 0; tg < NTG; tg++) {
      int t = tbase + tg * 16 + m15;
      bool valid = t < T;
      f32x4 d = dacc[g][tg];
      if (valid) {
        half4 h;
#pragma unroll
        for (int r = 0; r < 4; r++) h[r] = (_Float16)d[r];
        *(half4*)(outb + (size_t)t * C + (og0 + g) * 16 + quad * 4) = h;
      }
#pragma unroll
      for (int r = 0; r < 4; r++) {
        float v = valid ? d[r] : 0.f;
        rs[r] += v;
        rq[r] += v * v;
      }
    }
#pragma unroll
    for (int sh = 1; sh < 16; sh <<= 1) {
#pragma unroll
      for (int r = 0; r < 4; r++) {
        rs[r] += __shfl_xor(rs[r], sh);
        rq[r] += __shfl_xor(rq[r], sh);
      }
    }
    if (m15 == 0) {
      int o = (og0 + g) * 16 + quad * 4;
#pragma unroll
      for (int r = 0; r < 4; r++) {
        atomicAdd(&ssum[o + r], rs[r]);
        atomicAdd(&ssq[o + r], rq[r]);
      }
    }
  }
}

// ---------------------------------------------------------------------------
// Fused conv1 (KW=9, PAD=4) + conv3 (KW=1), 512 threads = 8 waves:
// wave wv -> og0=(wv&3)*2 (o-pair), t-half=(wv>>2) (tr0 = 0 or 32).
// 32 waves/CU (4 blocks x 8 waves) for latency hiding; A-frag duplicates
// between t-half wave pairs hit the same CU's L1. conv3 runs first so its
// accumulator retires before the 36 conv1 rounds (VGPR peak <= 64).
// fp16 in (zi16, pure-copy staging), fp16 out.
// ---------------------------------------------------------------------------
__global__ __launch_bounds__(512, 8) void conv13(
    const _Float16* __restrict__ in, const _Float16* __restrict__ w9,
    const _Float16* __restrict__ w1, _Float16* __restrict__ out1,
    _Float16* __restrict__ out3, float* __restrict__ gS1,
    float* __restrict__ gQ1, float* __restrict__ gS3,
    float* __restrict__ gQ3) {
  constexpr int PAD = 4;
  constexpr int ROWS = NT + 8;  // 72
  __shared__ __align__(16) _Float16 sh[ROWS * WPAD];
  __shared__ float ssum1[C], ssq1[C], ssum3[C], ssq3[C];

  const int tid = threadIdx.x;
  const int tile = blockIdx.x;
  const int b = blockIdx.y;
  const int t0 = tile * NT;

  if (tid < 128) {
    ssum1[tid] = 0.f; ssq1[tid] = 0.f;
    ssum3[tid] = 0.f; ssq3[tid] = 0.f;
  }

  // Stage fp16 rows [t0-PAD, t0-PAD+ROWS) — pure copy, 16B loads.
  const _Float16* __restrict__ inb = in + (size_t)b * T * C;
  for (int e = tid; e < ROWS * 16; e += 512) {
    int r = e >> 4;
    int c8 = e & 15;
    int t = t0 - PAD + r;
    half8 v = h8zero();
    if (t >= 0 && t < T) v = *(const half8*)(inb + (size_t)t * C + c8 * 8);
    *(half8*)&sh[r * WPAD + c8 * 8] = v;
  }
  __syncthreads();

  const int wv = tid >> 6;
  const int lane = tid & 63;
  const int quad = lane >> 4;
  const int m15 = lane & 15;
  const int og0 = (wv & 3) * 2;
  const int tr0 = (wv >> 2) * 32;

  const half8* __restrict__ A9 = (const half8*)w9;
  const half8* __restrict__ A1 = (const half8*)w1;

  // --- conv3 (KW=1): 4 rounds, retire early ---
  {
    f32x4 d3[2][2];
#pragma unroll
    for (int g = 0; g < 2; g++)
#pragma unroll
      for (int tg = 0; tg < 2; tg++) d3[g][tg] = f32x4{0.f, 0.f, 0.f, 0.f};
#pragma unroll
    for (int ic = 0; ic < 4; ic++) {
      const int kof = ic * 32 + quad * 8;
      half8 af[2];
#pragma unroll
      for (int g = 0; g < 2; g++)
        af[g] = A1[(ic * 4 + quad) * C + (og0 + g) * 16 + m15];
      half8 bf[2];
#pragma unroll
      for (int tg = 0; tg < 2; tg++)
        bf[tg] = *(const half8*)(sh + (tr0 + tg * 16 + m15 + PAD) * WPAD + kof);
#pragma unroll
      for (int g = 0; g < 2; g++)
#pragma unroll
        for (int tg = 0; tg < 2; tg++)
          d3[g][tg] = __builtin_amdgcn_mfma_f32_16x16x32_f16(
              af[g], bf[tg], d3[g][tg], 0, 0, 0);
    }
    _Float16* __restrict__ o3b = out3 + (size_t)b * T * C;
    store_and_stats_h<2, 2>(d3, o3b, ssum3, ssq3, t0 + tr0, og0, quad, m15);
  }

  // --- conv1 (KW=9): 36 rounds ---
  f32x4 d1[2][2];
#pragma unroll
  for (int g = 0; g < 2; g++)
#pragma unroll
    for (int tg = 0; tg < 2; tg++) d1[g][tg] = f32x4{0.f, 0.f, 0.f, 0.f};

  for (int kw = 0; kw < 9; kw++) {
#pragma unroll
    for (int ic = 0; ic < 4; ic++) {
      const int kof = ic * 32 + quad * 8;
      half8 af[2];
#pragma unroll
      for (int g = 0; g < 2; g++)
        af[g] = A9[(kw * 16 + ic * 4 + quad) * C + (og0 + g) * 16 + m15];
      half8 bf[2];
#pragma unroll
      for (int tg = 0; tg < 2; tg++)
        bf[tg] = *(const half8*)(sh + (tr0 + tg * 16 + m15 + kw) * WPAD + kof);
#pragma unroll
      for (int g = 0; g < 2; g++)
#pragma unroll
        for (int tg = 0; tg < 2; tg++)
          d1[g][tg] = __builtin_amdgcn_mfma_f32_16x16x32_f16(
              af[g], bf[tg], d1[g][tg], 0, 0, 0);
    }
  }

  _Float16* __restrict__ o1b = out1 + (size_t)b * T * C;
  store_and_stats_h<2, 2>(d1, o1b, ssum1, ssq1, t0 + tr0, og0, quad, m15);
  __syncthreads();
  if (tid < 128) {
    atomicAdd(&gS1[tid], ssum1[tid]);
    atomicAdd(&gQ1[tid], ssq1[tid]);
    atomicAdd(&gS3[tid], ssum3[tid]);
    atomicAdd(&gQ3[tid], ssq3[tid]);
  }
}

// ---------------------------------------------------------------------------
// conv2 (KW=9, PAD=4): fp16 in (t1, BN+relu applied during staging from
// inline stats), fp16 out. Same 8-wave geometry.
// ---------------------------------------------------------------------------
__global__ __launch_bounds__(512, 8) void conv2_bn(
    const _Float16* __restrict__ in, const _Float16* __restrict__ wf,
    const float* __restrict__ bnS, const float* __restrict__ bnQ,
    _Float16* __restrict__ out, float* __restrict__ gS,
    float* __restrict__ gQ) {
  constexpr int KW = 9, PAD = 4;
  constexpr int ROWS = NT + KW - 1;  // 72
  __shared__ __align__(16) _Float16 sh[ROWS * WPAD];
  __shared__ float ssum[C], ssq[C];
  __shared__ float sbm[C], sbr[C];

  const int tid = threadIdx.x;
  const int tile = blockIdx.x;
  const int b = blockIdx.y;
  const int t0 = tile * NT;

  if (tid < 128) {
    const float invn = 1.f / 64000.f;
    float m = bnS[tid] * invn;
    sbm[tid] = m;
    sbr[tid] = rsqrtf(bnQ[tid] * invn - m * m + 1e-5f);
    ssum[tid] = 0.f;
    ssq[tid] = 0.f;
  }
  __syncthreads();

  const _Float16* __restrict__ inb = in + (size_t)b * T * C;
  for (int e = tid; e < ROWS * 16; e += 512) {
    int r = e >> 4;
    int c8 = e & 15;
    int t = t0 - PAD + r;
    half8 v = h8zero();
    if (t >= 0 && t < T) {
      half8 u = *(const half8*)(inb + (size_t)t * C + c8 * 8);
      int c = c8 * 8;
#pragma unroll
      for (int j = 0; j < 8; j++) {
        float f = (float)u[j];
        f = fmaxf((f - sbm[c + j]) * sbr[c + j], 0.f);
        v[j] = (_Float16)f;
      }
    }
    *(half8*)&sh[r * WPAD + c8 * 8] = v;
  }
  __syncthreads();

  const int wv = tid >> 6;
  const int lane = tid & 63;
  const int quad = lane >> 4;
  const int m15 = lane & 15;
  const int og0 = (wv & 3) * 2;
  const int tr0 = (wv >> 2) * 32;

  const half8* __restrict__ Af = (const half8*)wf;

  f32x4 dacc[2][2];
#pragma unroll
  for (int g = 0; g < 2; g++)
#pragma unroll
    for (int tg = 0; tg < 2; tg++) dacc[g][tg] = f32x4{0.f, 0.f, 0.f, 0.f};

  for (int kw = 0; kw < 9; kw++) {
#pragma unroll
    for (int ic = 0; ic < 4; ic++) {
      const int kof = ic * 32 + quad * 8;
      half8 af[2];
#pragma unroll
      for (int g = 0; g < 2; g++)
        af[g] = Af[(kw * 16 + ic * 4 + quad) * C + (og0 + g) * 16 + m15];
      half8 bf[2];
#pragma unroll
      for (int tg = 0; tg < 2; tg++)
        bf[tg] = *(const half8*)(sh + (tr0 + tg * 16 + m15 + kw) * WPAD + kof);
#pragma unroll
      for (int g = 0; g < 2; g++)
#pragma unroll
        for (int tg = 0; tg < 2; tg++)
          dacc[g][tg] = __builtin_amdgcn_mfma_f32_16x16x32_f16(
              af[g], bf[tg], dacc[g][tg], 0, 0, 0);
    }
  }

  _Float16* __restrict__ outb = out + (size_t)b * T * C;
  store_and_stats_h<2, 2>(dacc, outb, ssum, ssq, t0 + tr0, og0, quad, m15);
  __syncthreads();
  if (tid < 128) {
    atomicAdd(&gS[tid], ssum[tid]);
    atomicAdd(&gQ[tid], ssq[tid]);
  }
}

// ---------------------------------------------------------------------------
// conv0: single fp16 16x16x32 MFMA. in x[B][80][T] (t fastest), K=96(pad) x 3.
// Output z fp32 (state). 256 threads, one dispatch — unchanged.
// ---------------------------------------------------------------------------
__global__ __launch_bounds__(256) void conv0_mfma(
    const float* __restrict__ in, const _Float16* __restrict__ wf,
    float* __restrict__ out, float* __restrict__ gS, float* __restrict__ gQ) {
  constexpr int KW = 3, PAD = 1;
  constexpr int ROWS = NT + KW - 1;  // 66
  __shared__ __align__(16) _Float16 sh[ROWS * IPAD0];
  __shared__ float ssum[C], ssq[C];

  const int tid = threadIdx.x;
  const int tile = blockIdx.x;
  const int b = blockIdx.y;
  const int t0 = tile * NT;

  if (tid < 128) { ssum[tid] = 0.f; ssq[tid] = 0.f; }
  __syncthreads();

  const float* __restrict__ inb = in + (size_t)b * CIN * T;
  for (int e = tid; e < I0 * ROWS; e += 256) {
    int i = e / ROWS;
    int r = e % ROWS;
    int t = t0 - PAD + r;
    float v = 0.f;
    if (i < CIN && t >= 0 && t < T) v = inb[(size_t)i * T + t];
    sh[r * IPAD0 + i] = (_Float16)v;
  }
  __syncthreads();

  const int wv = tid >> 6;
  const int lane = tid & 63;
  const int quad = lane >> 4;
  const int m15 = lane & 15;
  const int og0 = wv * 2;

  f32x4 dacc[2][4];
#pragma unroll
  for (int g = 0; g < 2; g++)
#pragma unroll
    for (int tg = 0; tg < 4; tg++) dacc[g][tg] = f32x4{0.f, 0.f, 0.f, 0.f};

  for (int kw = 0; kw < KW; kw++) {
    const _Float16* __restrict__ wk = wf + (size_t)kw * C * I0;
#pragma unroll
    for (int ic = 0; ic < 3; ic++) {
      const int kof = ic * 32 + quad * 8;
      half8 af[2];
#pragma unroll
      for (int g = 0; g < 2; g++) {
        size_t off = (size_t)((og0 + g) * 16 + m15) * I0 + kof;
        af[g] = *(const half8*)(wk + off);
      }
      half8 bf[4];
#pragma unroll
      for (int tg = 0; tg < 4; tg++) {
        int off = (tg * 16 + m15 + kw) * IPAD0 + kof;
        bf[tg] = *(const half8*)(sh + off);
      }
#pragma unroll
      for (int g = 0; g < 2; g++)
#pragma unroll
        for (int tg = 0; tg < 4; tg++)
          dacc[g][tg] = __builtin_amdgcn_mfma_f32_16x16x32_f16(
              af[g], bf[tg], dacc[g][tg], 0, 0, 0);
    }
  }

  float* __restrict__ outb = out + (size_t)b * T * C;
  store_and_stats_f<2, 4>(dacc, outb, ssum, ssq, t0, og0, quad, m15);
  __syncthreads();
  if (tid < 128) {
    atomicAdd(&gS[tid], ssum[tid]);
    atomicAdd(&gQ[tid], ssq[tid]);
  }
}

// ---------------------------------------------------------------------------
// z = relu((z - m[c]) * r[c]) in place (fp32) + fp16 snapshot for conv13.
// ---------------------------------------------------------------------------
__global__ __launch_bounds__(256) void apply_bn_relu(
    float* __restrict__ x, const float* __restrict__ S,
    const float* __restrict__ Q, _Float16* __restrict__ zh) {
  __shared__ float sm[C], sr[C];
  if (threadIdx.x < 128) {
    const float invn = 1.f / 64000.f;
    float m = S[threadIdx.x] * invn;
    sm[threadIdx.x] = m;
    sr[threadIdx.x] = rsqrtf(Q[threadIdx.x] * invn - m * m + 1e-5f);
  }
  __syncthreads();
  const size_t total4 = NBCT / 4;
  size_t stride = (size_t)gridDim.x * 256;
  for (size_t i4 = (size_t)blockIdx.x * 256 + threadIdx.x; i4 < total4;
       i4 += stride) {
    int c = (int)((i4 & 31) * 4);
    float4 v = ((float4*)x)[i4];
    v.x = fmaxf((v.x - sm[c]) * sr[c], 0.f);
    v.y = fmaxf((v.y - sm[c + 1]) * sr[c + 1], 0.f);
    v.z = fmaxf((v.z - sm[c + 2]) * sr[c + 2], 0.f);
    v.w = fmaxf((v.w - sm[c + 3]) * sr[c + 3], 0.f);
    ((float4*)x)[i4] = v;
    half4 h;
    h[0] = (_Float16)v.x;
    h[1] = (_Float16)v.y;
    h[2] = (_Float16)v.z;
    h[3] = (_Float16)v.w;
    *(half4*)(zh + i4 * 4) = h;
  }
}

// ---------------------------------------------------------------------------
// combine: k = relu(bn2(t2) + relu(bn3(t3))); RK4 update.
// t2/t3 fp16; z/acc fp32; zi16 (fp16 next-conv input) always written;
// z (fp32 state) written only on fin.
// ---------------------------------------------------------------------------
__global__ __launch_bounds__(256) void combine_kernel(
    const _Float16* __restrict__ t2, const _Float16* __restrict__ t3,
    const float* __restrict__ S2, const float* __restrict__ Q2,
    const float* __restrict__ S3, const float* __restrict__ Q3,
    float* __restrict__ z, float* __restrict__ acc,
    _Float16* __restrict__ zi16, float wacc, float anext, int init, int fin) {
  __shared__ float sm2[C], sr2[C], sm3[C], sr3[C];
  if (threadIdx.x < 128) {
    const float invn = 1.f / 64000.f;
    float m2v = S2[threadIdx.x] * invn;
    sm2[threadIdx.x] = m2v;
    sr2[threadIdx.x] = rsqrtf(Q2[threadIdx.x] * invn - m2v * m2v + 1e-5f);
    float m3v = S3[threadIdx.x] * invn;
    sm3[threadIdx.x] = m3v;
    sr3[threadIdx.x] = rsqrtf(Q3[threadIdx.x] * invn - m3v * m3v + 1e-5f);
  }
  __syncthreads();
  const size_t total4 = NBCT / 4;
  size_t stride = (size_t)gridDim.x * 256;
  for (size_t i4 = (size_t)blockIdx.x * 256 + threadIdx.x; i4 < total4;
       i4 += stride) {
    int c = (int)((i4 & 31) * 4);
    size_t off = i4 * 4;
    half4 h2 = *(const half4*)(t2 + off);
    half4 h3 = *(const half4*)(t3 + off);
    float4 vz = *(const float4*)(z + off);
    float k[4];
#pragma unroll
    for (int j = 0; j < 4; j++) {
      float f2 = (float)h2[j];
      float f3 = (float)h3[j];
      k[j] = fmaxf((f2 - sm2[c + j]) * sr2[c + j] +
                       fmaxf((f3 - sm3[c + j]) * sr3[c + j], 0.f),
                   0.f);
    }
    float va[4];
    if (init) {
#pragma unroll
      for (int j = 0; j < 4; j++) va[j] = wacc * k[j];
    } else {
      float4 a = *(const float4*)(acc + off);
      va[0] = a.x + wacc * k[0];
      va[1] = a.y + wacc * k[1];
      va[2] = a.z + wacc * k[2];
      va[3] = a.w + wacc * k[3];
    }
    float vzf[4] = {vz.x, vz.y, vz.z, vz.w};
    float vo[4];
    if (fin) {
#pragma unroll
      for (int j = 0; j < 4; j++) vo[j] = vzf[j] + anext * va[j];
      float4 w4 = make_float4(vo[0], vo[1], vo[2], vo[3]);
      *(float4*)(z + off) = w4;
    } else {
      float4 a4 = make_float4(va[0], va[1], va[2], va[3]);
      *(float4*)(acc + off) = a4;
#pragma unroll
      for (int j = 0; j < 4; j++) vo[j] = vzf[j] + anext * k[j];
    }
    half4 ho;
#pragma unroll
    for (int j = 0; j < 4; j++) ho[j] = (_Float16)vo[j];
    *(half4*)(zi16 + off) = ho;
  }
}

// ---------------------------------------------------------------------------
// head, phase 1: partial t-sums. grid (B, 4), each block sums 125 t's.
// ---------------------------------------------------------------------------
__global__ __launch_bounds__(256) void feat_part(
    const float* __restrict__ z, float* __restrict__ fp) {
  const int b = blockIdx.x;
  const int s = blockIdx.y;
  const int c = threadIdx.x & 127;
  const int h = threadIdx.x >> 7;
  const float* zb = z + (size_t)b * T * C;
  float sum = 0.f;
  for (int t = s * 125 + h; t < (s + 1) * 125; t += 2)
    sum += zb[(size_t)t * C + c];
  __shared__ float sf[2][C];
  sf[h][c] = sum;
  __syncthreads();
  if (threadIdx.x < 128)
    fp[((size_t)b * 4 + s) * C + threadIdx.x] =
        sf[0][threadIdx.x] + sf[1][threadIdx.x];
}

// head, phase 2: feat = sum(partials)/500; out = feat @ ow^T + ob.
__global__ __launch_bounds__(256) void head2(
    const float* __restrict__ fp, const float* __restrict__ ow,
    const float* __restrict__ ob, float* __restrict__ out) {
  const int b = blockIdx.x;
  __shared__ float feat[C];
  if (threadIdx.x < 128) {
    float s = 0.f;
#pragma unroll
    for (int p = 0; p < 4; p++) s += fp[((size_t)b * 4 + p) * C + threadIdx.x];
    feat[threadIdx.x] = s * (1.f / 500.f);
  }
  __syncthreads();
  if (threadIdx.x < NL) {
    int l = threadIdx.x;
    float o = ob[l];
    for (int j = 0; j < C; j++) o = fmaf(feat[j], ow[l * C + j], o);
    out[b * NL + l] = o;
  }
}

// ---------------------------------------------------------------------------
extern "C" void kernel_launch(void* const* d_in, const int* in_sizes, int n_in,
                              void* d_out, int out_size, void* d_ws,
                              size_t ws_size, hipStream_t stream) {
  const float* x  = (const float*)d_in[0];
  const float* w0 = (const float*)d_in[1];
  const float* w1 = (const float*)d_in[2];
  const float* w2 = (const float*)d_in[3];
  const float* w3 = (const float*)d_in[4];
  const float* ow = (const float*)d_in[5];
  const float* ob = (const float*)d_in[6];
  float* out = (float*)d_out;

  static float *z, *acc, *Sg, *Qg, *featp;
  static _Float16 *zi16, *t1, *t2, *t3;
  static _Float16 *w0f, *w1f, *w2f, *w3f;
  static bool inited = false;
  if (!inited) {
    void* p;
#define GET(sym, var) hipGetSymbolAddress(&p, HIP_SYMBOL(sym)); var = (decltype(var))p;
    GET(g_z, z) GET(g_acc, acc) GET(g_zi16, zi16)
    GET(g_t1, t1) GET(g_t2, t2) GET(g_t3, t3)
    GET(g_S, Sg) GET(g_Q, Qg) GET(g_featp, featp)
    GET(g_w0f, w0f) GET(g_w1f, w1f) GET(g_w2f, w2f) GET(g_w3f, w3f)
#undef GET
    inited = true;
  }

  // Zero stat slots + weight prep (cheap, every launch)
  zero_stats<<<(NSLOT * C + 255) / 256, 256, 0, stream>>>(Sg, Qg);
  prep_w0_f16<<<(3 * C * I0 + 255) / 256, 256, 0, stream>>>(w0, w0f);
  prep_weights_f16<9><<<(C * C * 9 + 255) / 256, 256, 0, stream>>>(w1, w1f);
  prep_weights_f16<9><<<(C * C * 9 + 255) / 256, 256, 0, stream>>>(w2, w2f);
  prep_weights_f16<1><<<(C * C * 1 + 255) / 256, 256, 0, stream>>>(w3, w3f);

  const dim3 convGrid(8, B);   // 1024 blocks; 512-thr -> 32 waves/CU
  const int ewGrid = 1024;
  const float dt = 0.25f;

  // conv0 -> bn -> relu (into z fp32 + zi16 fp16). Stats slot 48.
  float* S0 = Sg + 48 * C;
  float* Q0 = Qg + 48 * C;
  conv0_mfma<<<convGrid, 256, 0, stream>>>(x, w0f, z, S0, Q0);
  apply_bn_relu<<<ewGrid, 256, 0, stream>>>(z, S0, Q0, zi16);

  const float waccs[4] = {1.f, 2.f, 2.f, 1.f};
  const float anexts[4] = {0.5f * dt, 0.5f * dt, dt, dt / 6.f};

  for (int step = 0; step < 4; step++) {
    for (int s = 0; s < 4; s++) {
      int base = ((step * 4 + s) * 3) * C;   // slots: t1, t3, t2
      float* S1 = Sg + base;       float* Q1 = Qg + base;
      float* S3 = Sg + base + C;   float* Q3 = Qg + base + C;
      float* S2 = Sg + base + 2*C; float* Q2 = Qg + base + 2*C;
      conv13<<<convGrid, 512, 0, stream>>>(
          zi16, w1f, w3f, t1, t3, S1, Q1, S3, Q3);
      conv2_bn<<<convGrid, 512, 0, stream>>>(
          t1, w2f, S1, Q1, t2, S2, Q2);
      combine_kernel<<<ewGrid, 256, 0, stream>>>(
          t2, t3, S2, Q2, S3, Q3, z, acc, zi16,
          waccs[s], anexts[s], (s == 0) ? 1 : 0, (s == 3) ? 1 : 0);
    }
  }

  feat_part<<<dim3(B, 4), 256, 0, stream>>>(z, featp);
  head2<<<B, 256, 0, stream>>>(featp, ow, ob, out);
}